// Round 7
// baseline (591.100 us; speedup 1.0000x reference)
//
#include <hip/hip_runtime.h>

// Anti-alias filter: reflect-pad -> grouped conv (256->72, G=8, 3x3) -> BN ->
// softmax(72) -> per-pixel 9-tap weighted sum per channel.
// Shapes fixed: N=16, C=256, H=W=128, G=8, K=3, NCH=G*K*K=72, CPG=32.
//
// v6b: DS-free inner loops (v6 retry with derisked launch config).
// v4b==v5 (250us) despite 2x instruction-count difference => per-iteration
// latency bound: shfl (ds_bpermute) results share lgkmcnt with the
// wave-uniform weight s_loads (SMEM is out-of-order), so every iteration
// pays a full lgkmcnt(0) drain. Horizontal neighbors now come from 2 extra
// 4B vmem loads with reflection folded into per-lane ADDRESSES
// (offL = tl==0 ? +1 : -1, offR = tl==31 ? +2 : +4); all byte-offsets
// loop-invariant. Vector waits become fine-grained vmcnt(N); scalar weight
// loads drain lgkmcnt independently. Wave = one group x 2 rows, 4 px/lane.
// Softmax: per-group (m,S), ONE barrier, f4 LDS exchange.
// (v6 aborted at runtime; suspects were __launch_bounds__(512,8) VGPR cap
// and forced unroll — both reverted to v5's proven config.)

#define NN    16
#define CTOT  256
#define HH    128
#define WW    128
#define NG    8
#define CPG   32      // channels per group
#define NCH   72      // G*K*K conv output channels
#define BN_EPS 1e-5f

typedef float f4 __attribute__((ext_vector_type(4)));

// ---- prep: BN scale/bias into ws ----
// ws layout (floats): [0,72) = scale, [72,144) = bias.
__global__ void aaf_prep(const float* __restrict__ gamma,
                         const float* __restrict__ beta,
                         const float* __restrict__ rmean,
                         const float* __restrict__ rvar,
                         float* __restrict__ ws) {
    int t = threadIdx.x;
    if (t < NCH) {
        float sc = gamma[t] * rsqrtf(rvar[t] + BN_EPS);
        ws[t]       = sc;
        ws[NCH + t] = beta[t] - rmean[t] * sc;
    }
}

// ---- main: block = 8 waves = 8 groups; wave = 2 rows x 128 px (4 px/lane) ----
__global__ __launch_bounds__(512, 4) void aaf_main(
    const float* __restrict__ x,
    const float* __restrict__ wf,     // fp32 conv weights OIHW flat (wave-uniform -> s_load)
    const float* __restrict__ scale,  // fp32 BN scale (72)
    const float* __restrict__ bias,   // fp32 BN bias  (72)
    float* __restrict__ out) {

    __shared__ f4 red_m[NG][64];      // per-group softmax max, 4 px per slot (8 KB)
    __shared__ f4 red_s[NG][64];      // per-group exp-sum (8 KB)

    int t  = threadIdx.x & 63;                                     // lane
    int g  = __builtin_amdgcn_readfirstlane((int)threadIdx.x >> 6);// group = wave id
    int half = t >> 5;                // 0: row A, 1: row B
    int tl   = t & 31;                // lane within row
    int w0   = tl << 2;               // first of this lane's 4 pixels

    // 1024 blocks = one row-pair each; bijective XCD-chunked swizzle: each XCD
    // walks 128 consecutive row-pairs (2 images) -> vertical halo reuse in-L2.
    int bid = blockIdx.x;
    int pr  = (bid & 7) * (1024 / 8) + (bid >> 3);
    int n   = pr >> 6;                // 64 row-pairs per image
    int h   = ((pr & 63) << 1) + half;

    // reflection-pad row indices (pad=1): -1 -> 1, 128 -> 126
    int ys[3];
    ys[0] = (h == 0)   ? 1   : h - 1;
    ys[1] = h;
    ys[2] = (h == 127) ? 126 : h + 1;

    // horizontal reflection folded into per-lane load offsets:
    //   left neighbor  x[w0-1]: tl==0 -> x[1]   (== reflect(x[-1]))
    //   right neighbor x[w0+4]: tl==31 -> x[126] (== reflect(x[128]))
    int offL = (tl == 0)  ? (w0 + 1) : (w0 - 1);
    int offR = (tl == 31) ? (w0 + 2) : (w0 + 4);

    // this wave's 32 input channels start at g*CPG
    const float* xg = x + ((size_t)n << 22) + ((size_t)(g * CPG) << 14);

    float s0[9], s1[9], s2[9], s3[9];
#pragma unroll
    for (int o = 0; o < 9; o++) { s0[o] = 0.f; s1[o] = 0.f; s2[o] = 0.f; s3[o] = 0.f; }

    // ---- grouped conv: per (ci) 9 independent vmem loads, zero DS ops ----
    for (int ci = 0; ci < CPG; ci++) {
        const float* xc = xg + ((size_t)ci << 14);
        const float* wb = wf + (size_t)(g * 9) * (CPG * 9) + ci * 9;
        // issue all 9 loads up front (independent, vmcnt-tracked)
        f4 v[3]; float lv[3], rv[3];
#pragma unroll
        for (int ky = 0; ky < 3; ky++) {
            int rb = ys[ky] << 7;
            v[ky]  = *reinterpret_cast<const f4*>(xc + rb + w0);
            lv[ky] = xc[rb + offL];
            rv[ky] = xc[rb + offR];
        }
#pragma unroll
        for (int ky = 0; ky < 3; ky++) {
            float l = lv[ky], r = rv[ky];
            f4 vv = v[ky];
#pragma unroll
            for (int o = 0; o < 9; o++) {
                float wk0 = wb[o * (CPG * 9) + ky * 3 + 0];
                float wk1 = wb[o * (CPG * 9) + ky * 3 + 1];
                float wk2 = wb[o * (CPG * 9) + ky * 3 + 2];
                s0[o] = fmaf(l,    wk0, fmaf(vv.x, wk1, fmaf(vv.y, wk2, s0[o])));
                s1[o] = fmaf(vv.x, wk0, fmaf(vv.y, wk1, fmaf(vv.z, wk2, s1[o])));
                s2[o] = fmaf(vv.y, wk0, fmaf(vv.z, wk1, fmaf(vv.w, wk2, s2[o])));
                s3[o] = fmaf(vv.z, wk0, fmaf(vv.w, wk1, fmaf(r,    wk2, s3[o])));
            }
        }
    }

    // ---- BN + per-group (unnormalized) softmax over this group's 9 ----
    float m0 = -3.0e38f, m1 = -3.0e38f, m2 = -3.0e38f, m3 = -3.0e38f;
#pragma unroll
    for (int o = 0; o < 9; o++) {
        float sc = scale[g * 9 + o], bi = bias[g * 9 + o];
        s0[o] = fmaf(s0[o], sc, bi);  m0 = fmaxf(m0, s0[o]);
        s1[o] = fmaf(s1[o], sc, bi);  m1 = fmaxf(m1, s1[o]);
        s2[o] = fmaf(s2[o], sc, bi);  m2 = fmaxf(m2, s2[o]);
        s3[o] = fmaf(s3[o], sc, bi);  m3 = fmaxf(m3, s3[o]);
    }
    float S0 = 0.f, S1 = 0.f, S2 = 0.f, S3 = 0.f;
#pragma unroll
    for (int o = 0; o < 9; o++) {
        s0[o] = __expf(s0[o] - m0);  S0 += s0[o];   // s* now holds E
        s1[o] = __expf(s1[o] - m1);  S1 += s1[o];
        s2[o] = __expf(s2[o] - m2);  S2 += s2[o];
        s3[o] = __expf(s3[o] - m3);  S3 += s3[o];
    }
    {
        f4 mm; mm.x = m0; mm.y = m1; mm.z = m2; mm.w = m3;
        f4 ss; ss.x = S0; ss.y = S1; ss.z = S2; ss.w = S3;
        red_m[g][t] = mm;             // slot t = pixels [half*128 + w0 .. +3]
        red_s[g][t] = ss;
    }

    // ---- single barrier: combine the 8 groups' (m,S) into 1/denom ----
    __syncthreads();
    float d0 = 0.f, d1 = 0.f, d2 = 0.f, d3 = 0.f;
#pragma unroll
    for (int rg = 0; rg < NG; rg++) {
        f4 mm = red_m[rg][t];
        f4 ss = red_s[rg][t];
        d0 += ss.x * __expf(mm.x - m0);
        d1 += ss.y * __expf(mm.y - m1);
        d2 += ss.z * __expf(mm.z - m2);
        d3 += ss.w * __expf(mm.w - m3);
    }
    float i0 = 1.f / d0, i1 = 1.f / d1, i2 = 1.f / d2, i3 = 1.f / d3;
#pragma unroll
    for (int o = 0; o < 9; o++) { s0[o] *= i0; s1[o] *= i1; s2[o] *= i2; s3[o] *= i3; }

    // ---- weighted 9-tap sum for this wave's 32 channels (DS-free too) ----
    size_t obase = ((size_t)n << 22) + ((size_t)(g * CPG) << 14)
                 + ((size_t)h << 7) + (size_t)w0;
    for (int ci = 0; ci < CPG; ci++) {
        const float* xc = xg + ((size_t)ci << 14);
        float o0 = 0.f, o1 = 0.f, o2 = 0.f, o3 = 0.f;
#pragma unroll
        for (int ky = 0; ky < 3; ky++) {
            int rb = ys[ky] << 7;
            f4 vv   = *reinterpret_cast<const f4*>(xc + rb + w0);
            float l = xc[rb + offL];
            float r = xc[rb + offR];
            float e0 = s0[ky * 3 + 0], e1 = s0[ky * 3 + 1], e2 = s0[ky * 3 + 2];
            o0 = fmaf(l,    e0, fmaf(vv.x, e1, fmaf(vv.y, e2, o0)));
            e0 = s1[ky * 3 + 0]; e1 = s1[ky * 3 + 1]; e2 = s1[ky * 3 + 2];
            o1 = fmaf(vv.x, e0, fmaf(vv.y, e1, fmaf(vv.z, e2, o1)));
            e0 = s2[ky * 3 + 0]; e1 = s2[ky * 3 + 1]; e2 = s2[ky * 3 + 2];
            o2 = fmaf(vv.y, e0, fmaf(vv.z, e1, fmaf(vv.w, e2, o2)));
            e0 = s3[ky * 3 + 0]; e1 = s3[ky * 3 + 1]; e2 = s3[ky * 3 + 2];
            o3 = fmaf(vv.z, e0, fmaf(vv.w, e1, fmaf(r,    e2, o3)));
        }
        f4 ov; ov.x = o0; ov.y = o1; ov.z = o2; ov.w = o3;
        __builtin_nontemporal_store(ov,
            reinterpret_cast<f4*>(out + obase + ((size_t)ci << 14)));
    }
}

extern "C" void kernel_launch(void* const* d_in, const int* in_sizes, int n_in,
                              void* d_out, int out_size, void* d_ws, size_t ws_size,
                              hipStream_t stream) {
    const float* x     = (const float*)d_in[0];
    const float* cw    = (const float*)d_in[1];
    const float* gamma = (const float*)d_in[2];
    const float* beta  = (const float*)d_in[3];
    const float* rmean = (const float*)d_in[4];
    const float* rvar  = (const float*)d_in[5];
    float* out = (float*)d_out;
    float* ws  = (float*)d_ws;   // needs 144*4 = 576 B

    hipLaunchKernelGGL(aaf_prep, dim3(1), dim3(128), 0, stream,
                       gamma, beta, rmean, rvar, ws);

    int blocks = NN * HH / 2;           // 1024 blocks: one row-pair x 8 groups
    hipLaunchKernelGGL(aaf_main, dim3(blocks), dim3(512), 0, stream,
                       x, cw, ws, ws + NCH, out);
}

// Round 8
// 542.461 us; speedup vs baseline: 1.0897x; 1.0897x over previous
//
#include <hip/hip_runtime.h>

// Anti-alias filter: reflect-pad -> grouped conv (256->72, G=8, 3x3) -> BN ->
// softmax(72) -> per-pixel 9-tap weighted sum per channel.
// Shapes fixed: N=16, C=256, H=W=128, G=8, K=3, NCH=G*K*K=72, CPG=32.
//
// v7: contiguous bulk weight loads via ci-chunked conv loop.
// Diagnosis: v4b==v5==250us across 2x-different vmem/DS mixes; the shared
// serializer is the per-ci weight fetch: 9 non-contiguous 9-dword s_load
// clusters per ci, each with its own lgkmcnt wait guarding only 36 FMA
// (288 waits/wave at contended K$ latency ~ the missing 50% of wall time).
// Layout fact: for fixed (g,o), wf[(g*9+o)*288 + ci*9+tap] is CONTIGUOUS
// across (ci,tap). So: hold x for a chunk of 4 ci in registers (12 f4 +
// shfl neighbors), loop o inside — each (o,chunk) reads 36 contiguous
// uniform dwords (bulk s_load_dwordx16) with ONE wait guarding 144 FMA.
// Waits/wave: 288 -> 72. x path keeps v5's proven f4+shfl form.
// Phase 2 = v5's, with ci reversed (tail of phase 1 still L2-hot).

#define NN    16
#define CTOT  256
#define HH    128
#define WW    128
#define NG    8
#define CPG   32      // channels per group
#define NCH   72      // G*K*K conv output channels
#define BN_EPS 1e-5f

typedef float f4 __attribute__((ext_vector_type(4)));

// ---- prep: BN scale/bias into ws ----
// ws layout (floats): [0,72) = scale, [72,144) = bias.
__global__ void aaf_prep(const float* __restrict__ gamma,
                         const float* __restrict__ beta,
                         const float* __restrict__ rmean,
                         const float* __restrict__ rvar,
                         float* __restrict__ ws) {
    int t = threadIdx.x;
    if (t < NCH) {
        float sc = gamma[t] * rsqrtf(rvar[t] + BN_EPS);
        ws[t]       = sc;
        ws[NCH + t] = beta[t] - rmean[t] * sc;
    }
}

// ---- main: block = 8 waves = 8 groups; wave = 2 rows x 128 px (4 px/lane) ----
__global__ __launch_bounds__(512, 4) void aaf_main(
    const float* __restrict__ x,
    const float* __restrict__ wf,     // fp32 conv weights OIHW flat (wave-uniform -> s_load)
    const float* __restrict__ scale,  // fp32 BN scale (72)
    const float* __restrict__ bias,   // fp32 BN bias  (72)
    float* __restrict__ out) {

    __shared__ f4 red_m[NG][64];      // per-group softmax max, 4 px per slot (8 KB)
    __shared__ f4 red_s[NG][64];      // per-group exp-sum (8 KB)

    int t  = threadIdx.x & 63;                                     // lane
    int g  = __builtin_amdgcn_readfirstlane((int)threadIdx.x >> 6);// group = wave id
    int half = t >> 5;                // 0: row A, 1: row B
    int tl   = t & 31;                // lane within row
    int w0   = tl << 2;               // first of this lane's 4 pixels

    // 1024 blocks = one row-pair each; bijective XCD-chunked swizzle: each XCD
    // walks 128 consecutive row-pairs (2 images) -> vertical halo reuse in-L2.
    int bid = blockIdx.x;
    int pr  = (bid & 7) * (1024 / 8) + (bid >> 3);
    int n   = pr >> 6;                // 64 row-pairs per image
    int h   = ((pr & 63) << 1) + half;

    // reflection-pad row indices (pad=1): -1 -> 1, 128 -> 126
    int ys[3];
    ys[0] = (h == 0)   ? 1   : h - 1;
    ys[1] = h;
    ys[2] = (h == 127) ? 126 : h + 1;

    // this wave's 32 input channels start at g*CPG
    const float* xg = x + ((size_t)n << 22) + ((size_t)(g * CPG) << 14);

    float s0[9], s1[9], s2[9], s3[9];
#pragma unroll
    for (int o = 0; o < 9; o++) { s0[o] = 0.f; s1[o] = 0.f; s2[o] = 0.f; s3[o] = 0.f; }

    // ---- grouped conv, ci-chunked (4 ci per chunk) ----
    for (int cc = 0; cc < CPG / 4; cc++) {
        int ci0 = cc << 2;
        // load x for 4 channels x 3 rows: 12 f4 + neighbors via shfl
        f4 v[4][3]; float lv[4][3], rv[4][3];
#pragma unroll
        for (int j = 0; j < 4; j++) {
            const float* xc = xg + ((size_t)(ci0 + j) << 14);
#pragma unroll
            for (int ky = 0; ky < 3; ky++) {
                f4 vv = *reinterpret_cast<const f4*>(xc + (ys[ky] << 7) + w0);
                v[j][ky] = vv;
                float ll = __shfl_up(vv.w, 1);    // x[w0-1]
                lv[j][ky] = (tl == 0) ? vv.y : ll;    // left edge: reflect
                float rr = __shfl_down(vv.x, 1);  // x[w0+4]
                rv[j][ky] = (tl == 31) ? vv.z : rr;   // right edge: reflect
            }
        }
        // o-loop: weights for (g,o,ci0..ci0+3) are 36 CONTIGUOUS dwords
#pragma unroll
        for (int o = 0; o < 9; o++) {
            const float* wbo = wf + (size_t)(g * 9 + o) * (CPG * 9) + ci0 * 9;
            float a0 = s0[o], a1 = s1[o], a2 = s2[o], a3 = s3[o];
#pragma unroll
            for (int j = 0; j < 4; j++) {
#pragma unroll
                for (int ky = 0; ky < 3; ky++) {
                    float wk0 = wbo[j * 9 + ky * 3 + 0];
                    float wk1 = wbo[j * 9 + ky * 3 + 1];
                    float wk2 = wbo[j * 9 + ky * 3 + 2];
                    f4 vv = v[j][ky];
                    a0 = fmaf(lv[j][ky], wk0, fmaf(vv.x, wk1, fmaf(vv.y, wk2, a0)));
                    a1 = fmaf(vv.x,      wk0, fmaf(vv.y, wk1, fmaf(vv.z, wk2, a1)));
                    a2 = fmaf(vv.y,      wk0, fmaf(vv.z, wk1, fmaf(vv.w, wk2, a2)));
                    a3 = fmaf(vv.z,      wk0, fmaf(vv.w, wk1, fmaf(rv[j][ky], wk2, a3)));
                }
            }
            s0[o] = a0; s1[o] = a1; s2[o] = a2; s3[o] = a3;
        }
    }

    // ---- BN + per-group (unnormalized) softmax over this group's 9 ----
    float m0 = -3.0e38f, m1 = -3.0e38f, m2 = -3.0e38f, m3 = -3.0e38f;
#pragma unroll
    for (int o = 0; o < 9; o++) {
        float sc = scale[g * 9 + o], bi = bias[g * 9 + o];
        s0[o] = fmaf(s0[o], sc, bi);  m0 = fmaxf(m0, s0[o]);
        s1[o] = fmaf(s1[o], sc, bi);  m1 = fmaxf(m1, s1[o]);
        s2[o] = fmaf(s2[o], sc, bi);  m2 = fmaxf(m2, s2[o]);
        s3[o] = fmaf(s3[o], sc, bi);  m3 = fmaxf(m3, s3[o]);
    }
    float S0 = 0.f, S1 = 0.f, S2 = 0.f, S3 = 0.f;
#pragma unroll
    for (int o = 0; o < 9; o++) {
        s0[o] = __expf(s0[o] - m0);  S0 += s0[o];   // s* now holds E
        s1[o] = __expf(s1[o] - m1);  S1 += s1[o];
        s2[o] = __expf(s2[o] - m2);  S2 += s2[o];
        s3[o] = __expf(s3[o] - m3);  S3 += s3[o];
    }
    {
        f4 mm; mm.x = m0; mm.y = m1; mm.z = m2; mm.w = m3;
        f4 ss; ss.x = S0; ss.y = S1; ss.z = S2; ss.w = S3;
        red_m[g][t] = mm;             // slot t = pixels [half*128 + w0 .. +3]
        red_s[g][t] = ss;
    }

    // ---- single barrier: combine the 8 groups' (m,S) into 1/denom ----
    __syncthreads();
    float d0 = 0.f, d1 = 0.f, d2 = 0.f, d3 = 0.f;
#pragma unroll
    for (int rg = 0; rg < NG; rg++) {
        f4 mm = red_m[rg][t];
        f4 ss = red_s[rg][t];
        d0 += ss.x * __expf(mm.x - m0);
        d1 += ss.y * __expf(mm.y - m1);
        d2 += ss.z * __expf(mm.z - m2);
        d3 += ss.w * __expf(mm.w - m3);
    }
    float i0 = 1.f / d0, i1 = 1.f / d1, i2 = 1.f / d2, i3 = 1.f / d3;
#pragma unroll
    for (int o = 0; o < 9; o++) { s0[o] *= i0; s1[o] *= i1; s2[o] *= i2; s3[o] *= i3; }

    // ---- weighted 9-tap sum for this wave's 32 channels ----
    // ci reversed: the tail of phase 1 is still L2-resident.
    size_t obase = ((size_t)n << 22) + ((size_t)(g * CPG) << 14)
                 + ((size_t)h << 7) + (size_t)w0;
    for (int ci = CPG - 1; ci >= 0; ci--) {
        const float* xc = xg + ((size_t)ci << 14);
        float o0 = 0.f, o1 = 0.f, o2 = 0.f, o3 = 0.f;
#pragma unroll
        for (int ky = 0; ky < 3; ky++) {
            f4 vv = *reinterpret_cast<const f4*>(xc + (ys[ky] << 7) + w0);
            float l = __shfl_up(vv.w, 1);
            l = (tl == 0) ? vv.y : l;
            float r = __shfl_down(vv.x, 1);
            r = (tl == 31) ? vv.z : r;
            float e0 = s0[ky * 3 + 0], e1 = s0[ky * 3 + 1], e2 = s0[ky * 3 + 2];
            o0 = fmaf(l,    e0, fmaf(vv.x, e1, fmaf(vv.y, e2, o0)));
            e0 = s1[ky * 3 + 0]; e1 = s1[ky * 3 + 1]; e2 = s1[ky * 3 + 2];
            o1 = fmaf(vv.x, e0, fmaf(vv.y, e1, fmaf(vv.z, e2, o1)));
            e0 = s2[ky * 3 + 0]; e1 = s2[ky * 3 + 1]; e2 = s2[ky * 3 + 2];
            o2 = fmaf(vv.y, e0, fmaf(vv.z, e1, fmaf(vv.w, e2, o2)));
            e0 = s3[ky * 3 + 0]; e1 = s3[ky * 3 + 1]; e2 = s3[ky * 3 + 2];
            o3 = fmaf(vv.z, e0, fmaf(vv.w, e1, fmaf(r,    e2, o3)));
        }
        f4 ov; ov.x = o0; ov.y = o1; ov.z = o2; ov.w = o3;
        __builtin_nontemporal_store(ov,
            reinterpret_cast<f4*>(out + obase + ((size_t)ci << 14)));
    }
}

extern "C" void kernel_launch(void* const* d_in, const int* in_sizes, int n_in,
                              void* d_out, int out_size, void* d_ws, size_t ws_size,
                              hipStream_t stream) {
    const float* x     = (const float*)d_in[0];
    const float* cw    = (const float*)d_in[1];
    const float* gamma = (const float*)d_in[2];
    const float* beta  = (const float*)d_in[3];
    const float* rmean = (const float*)d_in[4];
    const float* rvar  = (const float*)d_in[5];
    float* out = (float*)d_out;
    float* ws  = (float*)d_ws;   // needs 144*4 = 576 B

    hipLaunchKernelGGL(aaf_prep, dim3(1), dim3(128), 0, stream,
                       gamma, beta, rmean, rvar, ws);

    int blocks = NN * HH / 2;           // 1024 blocks: one row-pair x 8 groups
    hipLaunchKernelGGL(aaf_main, dim3(blocks), dim3(512), 0, stream,
                       x, cw, ws, ws + NCH, out);
}

// Round 9
// 511.009 us; speedup vs baseline: 1.1567x; 1.0616x over previous
//
#include <hip/hip_runtime.h>

// Anti-alias filter: reflect-pad -> grouped conv (256->72, G=8, 3x3) -> BN ->
// softmax(72) -> per-pixel 9-tap weighted sum per channel.
// Shapes fixed: N=16, C=256, H=W=128, G=8, K=3, NCH=G*K*K=72, CPG=32.
//
// v8: packed-FP32 conv (v_pk_fma_f32 via f2 + __builtin_elementwise_fma).
// Evidence: v4b=v5=v7=250us across wildly different vmem/DS/weight-fetch
// structures; VALU busy time constant ~120us (~50% duty). => VALU
// instruction count is the binding resource. Packed fp32 pairs pixels
// (0,1) and (2,3): tap pairs {l,x},{x,y},{y,z},{z,w},{w,r} built once per
// (ci,ky), 9 outputs consume them -> phase-1 FMA instrs 324 -> 162/ci.
// Lowering falls back to 2 scalar fmas if gfx950 lacks VOP3P pk_fma
// (clean falsification). Accumulation order identical -> bit-same output.
// x path: f4 load + shfl neighbors (v5's proven form). Phase 2 scalar.

#define NN    16
#define CTOT  256
#define HH    128
#define WW    128
#define NG    8
#define CPG   32      // channels per group
#define NCH   72      // G*K*K conv output channels
#define BN_EPS 1e-5f

typedef float f2 __attribute__((ext_vector_type(2)));
typedef float f4 __attribute__((ext_vector_type(4)));

// ---- prep: BN scale/bias into ws ----
// ws layout (floats): [0,72) = scale, [72,144) = bias.
__global__ void aaf_prep(const float* __restrict__ gamma,
                         const float* __restrict__ beta,
                         const float* __restrict__ rmean,
                         const float* __restrict__ rvar,
                         float* __restrict__ ws) {
    int t = threadIdx.x;
    if (t < NCH) {
        float sc = gamma[t] * rsqrtf(rvar[t] + BN_EPS);
        ws[t]       = sc;
        ws[NCH + t] = beta[t] - rmean[t] * sc;
    }
}

// ---- main: block = 8 waves = 8 groups; wave = 2 rows x 128 px (4 px/lane) ----
__global__ __launch_bounds__(512) void aaf_main(
    const float* __restrict__ x,
    const float* __restrict__ wf,     // fp32 conv weights OIHW flat (wave-uniform -> s_load)
    const float* __restrict__ scale,  // fp32 BN scale (72)
    const float* __restrict__ bias,   // fp32 BN bias  (72)
    float* __restrict__ out) {

    __shared__ f4 red_m[NG][64];      // per-group softmax max, 4 px per slot (8 KB)
    __shared__ f4 red_s[NG][64];      // per-group exp-sum (8 KB)

    int t  = threadIdx.x & 63;                                     // lane
    int g  = __builtin_amdgcn_readfirstlane((int)threadIdx.x >> 6);// group = wave id
    int half = t >> 5;                // 0: row A, 1: row B
    int tl   = t & 31;                // lane within row
    int w0   = tl << 2;               // first of this lane's 4 pixels

    // 1024 blocks = one row-pair each; bijective XCD-chunked swizzle: each XCD
    // walks 128 consecutive row-pairs (2 images) -> vertical halo reuse in-L2.
    int bid = blockIdx.x;
    int pr  = (bid & 7) * (1024 / 8) + (bid >> 3);
    int n   = pr >> 6;                // 64 row-pairs per image
    int h   = ((pr & 63) << 1) + half;

    // reflection-pad row indices (pad=1): -1 -> 1, 128 -> 126
    int ys[3];
    ys[0] = (h == 0)   ? 1   : h - 1;
    ys[1] = h;
    ys[2] = (h == 127) ? 126 : h + 1;

    // this wave's 32 input channels start at g*CPG
    const float* xg = x + ((size_t)n << 22) + ((size_t)(g * CPG) << 14);

    f2 S01[9], S23[9];
#pragma unroll
    for (int o = 0; o < 9; o++) { S01[o] = (f2)0.f; S23[o] = (f2)0.f; }

    // ---- grouped conv, packed fp32: 5 tap-pairs per (ci,ky), 6 pk_fma per o ----
    for (int ci = 0; ci < CPG; ci++) {
        const float* xc = xg + ((size_t)ci << 14);
        const float* wb = wf + (size_t)(g * 9) * (CPG * 9) + ci * 9;
        f2 P[3][5];
#pragma unroll
        for (int ky = 0; ky < 3; ky++) {
            f4 vv = *reinterpret_cast<const f4*>(xc + (ys[ky] << 7) + w0);
            float l = __shfl_up(vv.w, 1);     // x[w0-1]
            l = (tl == 0) ? vv.y : l;         // left edge: reflect -> x[1]
            float r = __shfl_down(vv.x, 1);   // x[w0+4]
            r = (tl == 31) ? vv.z : r;        // right edge: reflect -> x[126]
            P[ky][0] = (f2){l,    vv.x};
            P[ky][1] = (f2){vv.x, vv.y};
            P[ky][2] = (f2){vv.y, vv.z};
            P[ky][3] = (f2){vv.z, vv.w};
            P[ky][4] = (f2){vv.w, r};
        }
#pragma unroll
        for (int o = 0; o < 9; o++) {
            const float* wo = wb + o * (CPG * 9);
            f2 a01 = S01[o], a23 = S23[o];
#pragma unroll
            for (int ky = 0; ky < 3; ky++) {
                f2 w0b = (f2)wo[ky * 3 + 0];   // scalar->vector splat
                f2 w1b = (f2)wo[ky * 3 + 1];
                f2 w2b = (f2)wo[ky * 3 + 2];
                a01 = __builtin_elementwise_fma(P[ky][0], w0b,
                      __builtin_elementwise_fma(P[ky][1], w1b,
                      __builtin_elementwise_fma(P[ky][2], w2b, a01)));
                a23 = __builtin_elementwise_fma(P[ky][2], w0b,
                      __builtin_elementwise_fma(P[ky][3], w1b,
                      __builtin_elementwise_fma(P[ky][4], w2b, a23)));
            }
            S01[o] = a01; S23[o] = a23;
        }
    }

    // ---- BN + per-group (unnormalized) softmax over this group's 9 ----
    float s0[9], s1[9], s2[9], s3[9];
    float m0 = -3.0e38f, m1 = -3.0e38f, m2 = -3.0e38f, m3 = -3.0e38f;
#pragma unroll
    for (int o = 0; o < 9; o++) {
        float sc = scale[g * 9 + o], bi = bias[g * 9 + o];
        s0[o] = fmaf(S01[o].x, sc, bi);  m0 = fmaxf(m0, s0[o]);
        s1[o] = fmaf(S01[o].y, sc, bi);  m1 = fmaxf(m1, s1[o]);
        s2[o] = fmaf(S23[o].x, sc, bi);  m2 = fmaxf(m2, s2[o]);
        s3[o] = fmaf(S23[o].y, sc, bi);  m3 = fmaxf(m3, s3[o]);
    }
    float S0 = 0.f, S1 = 0.f, S2 = 0.f, S3 = 0.f;
#pragma unroll
    for (int o = 0; o < 9; o++) {
        s0[o] = __expf(s0[o] - m0);  S0 += s0[o];   // s* now holds E
        s1[o] = __expf(s1[o] - m1);  S1 += s1[o];
        s2[o] = __expf(s2[o] - m2);  S2 += s2[o];
        s3[o] = __expf(s3[o] - m3);  S3 += s3[o];
    }
    {
        f4 mm; mm.x = m0; mm.y = m1; mm.z = m2; mm.w = m3;
        f4 ss; ss.x = S0; ss.y = S1; ss.z = S2; ss.w = S3;
        red_m[g][t] = mm;             // slot t = pixels [half*128 + w0 .. +3]
        red_s[g][t] = ss;
    }

    // ---- single barrier: combine the 8 groups' (m,S) into 1/denom ----
    __syncthreads();
    float d0 = 0.f, d1 = 0.f, d2 = 0.f, d3 = 0.f;
#pragma unroll
    for (int rg = 0; rg < NG; rg++) {
        f4 mm = red_m[rg][t];
        f4 ss = red_s[rg][t];
        d0 += ss.x * __expf(mm.x - m0);
        d1 += ss.y * __expf(mm.y - m1);
        d2 += ss.z * __expf(mm.z - m2);
        d3 += ss.w * __expf(mm.w - m3);
    }
    float i0 = 1.f / d0, i1 = 1.f / d1, i2 = 1.f / d2, i3 = 1.f / d3;
#pragma unroll
    for (int o = 0; o < 9; o++) { s0[o] *= i0; s1[o] *= i1; s2[o] *= i2; s3[o] *= i3; }

    // ---- weighted 9-tap sum for this wave's 32 channels ----
    // ci reversed: the tail of phase 1 is still L2-resident.
    size_t obase = ((size_t)n << 22) + ((size_t)(g * CPG) << 14)
                 + ((size_t)h << 7) + (size_t)w0;
    for (int ci = CPG - 1; ci >= 0; ci--) {
        const float* xc = xg + ((size_t)ci << 14);
        float o0 = 0.f, o1 = 0.f, o2 = 0.f, o3 = 0.f;
#pragma unroll
        for (int ky = 0; ky < 3; ky++) {
            f4 vv = *reinterpret_cast<const f4*>(xc + (ys[ky] << 7) + w0);
            float l = __shfl_up(vv.w, 1);
            l = (tl == 0) ? vv.y : l;
            float r = __shfl_down(vv.x, 1);
            r = (tl == 31) ? vv.z : r;
            float e0 = s0[ky * 3 + 0], e1 = s0[ky * 3 + 1], e2 = s0[ky * 3 + 2];
            o0 = fmaf(l,    e0, fmaf(vv.x, e1, fmaf(vv.y, e2, o0)));
            e0 = s1[ky * 3 + 0]; e1 = s1[ky * 3 + 1]; e2 = s1[ky * 3 + 2];
            o1 = fmaf(vv.x, e0, fmaf(vv.y, e1, fmaf(vv.z, e2, o1)));
            e0 = s2[ky * 3 + 0]; e1 = s2[ky * 3 + 1]; e2 = s2[ky * 3 + 2];
            o2 = fmaf(vv.y, e0, fmaf(vv.z, e1, fmaf(vv.w, e2, o2)));
            e0 = s3[ky * 3 + 0]; e1 = s3[ky * 3 + 1]; e2 = s3[ky * 3 + 2];
            o3 = fmaf(vv.z, e0, fmaf(vv.w, e1, fmaf(r,    e2, o3)));
        }
        f4 ov; ov.x = o0; ov.y = o1; ov.z = o2; ov.w = o3;
        __builtin_nontemporal_store(ov,
            reinterpret_cast<f4*>(out + obase + ((size_t)ci << 14)));
    }
}

extern "C" void kernel_launch(void* const* d_in, const int* in_sizes, int n_in,
                              void* d_out, int out_size, void* d_ws, size_t ws_size,
                              hipStream_t stream) {
    const float* x     = (const float*)d_in[0];
    const float* cw    = (const float*)d_in[1];
    const float* gamma = (const float*)d_in[2];
    const float* beta  = (const float*)d_in[3];
    const float* rmean = (const float*)d_in[4];
    const float* rvar  = (const float*)d_in[5];
    float* out = (float*)d_out;
    float* ws  = (float*)d_ws;   // needs 144*4 = 576 B

    hipLaunchKernelGGL(aaf_prep, dim3(1), dim3(128), 0, stream,
                       gamma, beta, rmean, rvar, ws);

    int blocks = NN * HH / 2;           // 1024 blocks: one row-pair x 8 groups
    hipLaunchKernelGGL(aaf_main, dim3(blocks), dim3(512), 0, stream,
                       x, cw, ws, ws + NCH, out);
}

// Round 10
// 501.777 us; speedup vs baseline: 1.1780x; 1.0184x over previous
//
#include <hip/hip_runtime.h>

// Anti-alias filter: reflect-pad -> grouped conv (256->72, G=8, 3x3) -> BN ->
// softmax(72) -> per-pixel 9-tap weighted sum per channel.
// Shapes fixed: N=16, C=256, H=W=128, G=8, K=3, NCH=G*K*K=72, CPG=32.
//
// v9: v8 (packed-FP32 conv) + explicit register double-buffer prefetch.
// v8 post-mortem: pk_fma cut wall 250->213us (VALU count IS binding) but
// duty stuck at ~53% and VGPR collapsed to 48 => compiler scheduled for
// minimal registers, no cross-iteration load pipelining: each ci pays a
// full L1 latency covered by only ~108cyc of pk_fma. Fix: prefetch ci+1's
// 3 f4 rows into a second register buffer before computing ci (both
// phases), #pragma unroll 2 to ping-pong buffers without movs. Loads for
// ci+1 are in flight during ci's FMA chain -> counted vmcnt waits.

#define NN    16
#define CTOT  256
#define HH    128
#define WW    128
#define NG    8
#define CPG   32      // channels per group
#define NCH   72      // G*K*K conv output channels
#define BN_EPS 1e-5f

typedef float f2 __attribute__((ext_vector_type(2)));
typedef float f4 __attribute__((ext_vector_type(4)));

// ---- prep: BN scale/bias into ws ----
// ws layout (floats): [0,72) = scale, [72,144) = bias.
__global__ void aaf_prep(const float* __restrict__ gamma,
                         const float* __restrict__ beta,
                         const float* __restrict__ rmean,
                         const float* __restrict__ rvar,
                         float* __restrict__ ws) {
    int t = threadIdx.x;
    if (t < NCH) {
        float sc = gamma[t] * rsqrtf(rvar[t] + BN_EPS);
        ws[t]       = sc;
        ws[NCH + t] = beta[t] - rmean[t] * sc;
    }
}

// ---- main: block = 8 waves = 8 groups; wave = 2 rows x 128 px (4 px/lane) ----
__global__ __launch_bounds__(512) void aaf_main(
    const float* __restrict__ x,
    const float* __restrict__ wf,     // fp32 conv weights OIHW flat (wave-uniform -> s_load)
    const float* __restrict__ scale,  // fp32 BN scale (72)
    const float* __restrict__ bias,   // fp32 BN bias  (72)
    float* __restrict__ out) {

    __shared__ f4 red_m[NG][64];      // per-group softmax max, 4 px per slot (8 KB)
    __shared__ f4 red_s[NG][64];      // per-group exp-sum (8 KB)

    int t  = threadIdx.x & 63;                                     // lane
    int g  = __builtin_amdgcn_readfirstlane((int)threadIdx.x >> 6);// group = wave id
    int half = t >> 5;                // 0: row A, 1: row B
    int tl   = t & 31;                // lane within row
    int w0   = tl << 2;               // first of this lane's 4 pixels

    // 1024 blocks = one row-pair each; bijective XCD-chunked swizzle: each XCD
    // walks 128 consecutive row-pairs (2 images) -> vertical halo reuse in-L2.
    int bid = blockIdx.x;
    int pr  = (bid & 7) * (1024 / 8) + (bid >> 3);
    int n   = pr >> 6;                // 64 row-pairs per image
    int h   = ((pr & 63) << 1) + half;

    // reflection-pad row indices (pad=1): -1 -> 1, 128 -> 126
    int ys[3];
    ys[0] = (h == 0)   ? 1   : h - 1;
    ys[1] = h;
    ys[2] = (h == 127) ? 126 : h + 1;

    // this wave's 32 input channels start at g*CPG
    const float* xg = x + ((size_t)n << 22) + ((size_t)(g * CPG) << 14);

    f2 S01[9], S23[9];
#pragma unroll
    for (int o = 0; o < 9; o++) { S01[o] = (f2)0.f; S23[o] = (f2)0.f; }

    // ---- grouped conv, packed fp32, ci+1 register prefetch ----
    f4 cur[3];
#pragma unroll
    for (int ky = 0; ky < 3; ky++)
        cur[ky] = *reinterpret_cast<const f4*>(xg + (ys[ky] << 7) + w0);

#pragma unroll 2
    for (int ci = 0; ci < CPG; ci++) {
        // prefetch next channel's 3 rows (last iter: reload current, harmless)
        int cin = (ci + 1 < CPG) ? ci + 1 : ci;
        const float* xcn = xg + ((size_t)cin << 14);
        f4 nxt[3];
#pragma unroll
        for (int ky = 0; ky < 3; ky++)
            nxt[ky] = *reinterpret_cast<const f4*>(xcn + (ys[ky] << 7) + w0);

        // build tap pairs from cur
        f2 P[3][5];
#pragma unroll
        for (int ky = 0; ky < 3; ky++) {
            f4 vv = cur[ky];
            float l = __shfl_up(vv.w, 1);     // x[w0-1]
            l = (tl == 0) ? vv.y : l;         // left edge: reflect -> x[1]
            float r = __shfl_down(vv.x, 1);   // x[w0+4]
            r = (tl == 31) ? vv.z : r;        // right edge: reflect -> x[126]
            P[ky][0] = (f2){l,    vv.x};
            P[ky][1] = (f2){vv.x, vv.y};
            P[ky][2] = (f2){vv.y, vv.z};
            P[ky][3] = (f2){vv.z, vv.w};
            P[ky][4] = (f2){vv.w, r};
        }
        const float* wb = wf + (size_t)(g * 9) * (CPG * 9) + ci * 9;
#pragma unroll
        for (int o = 0; o < 9; o++) {
            const float* wo = wb + o * (CPG * 9);
            f2 a01 = S01[o], a23 = S23[o];
#pragma unroll
            for (int ky = 0; ky < 3; ky++) {
                f2 w0b = (f2)wo[ky * 3 + 0];   // scalar->vector splat
                f2 w1b = (f2)wo[ky * 3 + 1];
                f2 w2b = (f2)wo[ky * 3 + 2];
                a01 = __builtin_elementwise_fma(P[ky][0], w0b,
                      __builtin_elementwise_fma(P[ky][1], w1b,
                      __builtin_elementwise_fma(P[ky][2], w2b, a01)));
                a23 = __builtin_elementwise_fma(P[ky][2], w0b,
                      __builtin_elementwise_fma(P[ky][3], w1b,
                      __builtin_elementwise_fma(P[ky][4], w2b, a23)));
            }
            S01[o] = a01; S23[o] = a23;
        }
#pragma unroll
        for (int ky = 0; ky < 3; ky++) cur[ky] = nxt[ky];
    }

    // ---- BN + per-group (unnormalized) softmax over this group's 9 ----
    float s0[9], s1[9], s2[9], s3[9];
    float m0 = -3.0e38f, m1 = -3.0e38f, m2 = -3.0e38f, m3 = -3.0e38f;
#pragma unroll
    for (int o = 0; o < 9; o++) {
        float sc = scale[g * 9 + o], bi = bias[g * 9 + o];
        s0[o] = fmaf(S01[o].x, sc, bi);  m0 = fmaxf(m0, s0[o]);
        s1[o] = fmaf(S01[o].y, sc, bi);  m1 = fmaxf(m1, s1[o]);
        s2[o] = fmaf(S23[o].x, sc, bi);  m2 = fmaxf(m2, s2[o]);
        s3[o] = fmaf(S23[o].y, sc, bi);  m3 = fmaxf(m3, s3[o]);
    }
    float S0 = 0.f, S1 = 0.f, S2 = 0.f, S3 = 0.f;
#pragma unroll
    for (int o = 0; o < 9; o++) {
        s0[o] = __expf(s0[o] - m0);  S0 += s0[o];   // s* now holds E
        s1[o] = __expf(s1[o] - m1);  S1 += s1[o];
        s2[o] = __expf(s2[o] - m2);  S2 += s2[o];
        s3[o] = __expf(s3[o] - m3);  S3 += s3[o];
    }
    {
        f4 mm; mm.x = m0; mm.y = m1; mm.z = m2; mm.w = m3;
        f4 ss; ss.x = S0; ss.y = S1; ss.z = S2; ss.w = S3;
        red_m[g][t] = mm;             // slot t = pixels [half*128 + w0 .. +3]
        red_s[g][t] = ss;
    }

    // ---- single barrier: combine the 8 groups' (m,S) into 1/denom ----
    __syncthreads();
    float d0 = 0.f, d1 = 0.f, d2 = 0.f, d3 = 0.f;
#pragma unroll
    for (int rg = 0; rg < NG; rg++) {
        f4 mm = red_m[rg][t];
        f4 ss = red_s[rg][t];
        d0 += ss.x * __expf(mm.x - m0);
        d1 += ss.y * __expf(mm.y - m1);
        d2 += ss.z * __expf(mm.z - m2);
        d3 += ss.w * __expf(mm.w - m3);
    }
    float i0 = 1.f / d0, i1 = 1.f / d1, i2 = 1.f / d2, i3 = 1.f / d3;
#pragma unroll
    for (int o = 0; o < 9; o++) { s0[o] *= i0; s1[o] *= i1; s2[o] *= i2; s3[o] *= i3; }

    // ---- weighted 9-tap sum, ci reversed (phase-1 tail L2-hot), prefetched ----
    size_t obase = ((size_t)n << 22) + ((size_t)(g * CPG) << 14)
                 + ((size_t)h << 7) + (size_t)w0;
    f4 cur2[3];
#pragma unroll
    for (int ky = 0; ky < 3; ky++)
        cur2[ky] = *reinterpret_cast<const f4*>(
            xg + ((size_t)(CPG - 1) << 14) + (ys[ky] << 7) + w0);

#pragma unroll 2
    for (int ci = CPG - 1; ci >= 0; ci--) {
        int cin = (ci > 0) ? ci - 1 : ci;
        const float* xcn = xg + ((size_t)cin << 14);
        f4 nxt[3];
#pragma unroll
        for (int ky = 0; ky < 3; ky++)
            nxt[ky] = *reinterpret_cast<const f4*>(xcn + (ys[ky] << 7) + w0);

        float o0 = 0.f, o1 = 0.f, o2 = 0.f, o3 = 0.f;
#pragma unroll
        for (int ky = 0; ky < 3; ky++) {
            f4 vv = cur2[ky];
            float l = __shfl_up(vv.w, 1);
            l = (tl == 0) ? vv.y : l;
            float r = __shfl_down(vv.x, 1);
            r = (tl == 31) ? vv.z : r;
            float e0 = s0[ky * 3 + 0], e1 = s0[ky * 3 + 1], e2 = s0[ky * 3 + 2];
            o0 = fmaf(l,    e0, fmaf(vv.x, e1, fmaf(vv.y, e2, o0)));
            e0 = s1[ky * 3 + 0]; e1 = s1[ky * 3 + 1]; e2 = s1[ky * 3 + 2];
            o1 = fmaf(vv.x, e0, fmaf(vv.y, e1, fmaf(vv.z, e2, o1)));
            e0 = s2[ky * 3 + 0]; e1 = s2[ky * 3 + 1]; e2 = s2[ky * 3 + 2];
            o2 = fmaf(vv.y, e0, fmaf(vv.z, e1, fmaf(vv.w, e2, o2)));
            e0 = s3[ky * 3 + 0]; e1 = s3[ky * 3 + 1]; e2 = s3[ky * 3 + 2];
            o3 = fmaf(vv.z, e0, fmaf(vv.w, e1, fmaf(r,    e2, o3)));
        }
        f4 ov; ov.x = o0; ov.y = o1; ov.z = o2; ov.w = o3;
        __builtin_nontemporal_store(ov,
            reinterpret_cast<f4*>(out + obase + ((size_t)ci << 14)));
#pragma unroll
        for (int ky = 0; ky < 3; ky++) cur2[ky] = nxt[ky];
    }
}

extern "C" void kernel_launch(void* const* d_in, const int* in_sizes, int n_in,
                              void* d_out, int out_size, void* d_ws, size_t ws_size,
                              hipStream_t stream) {
    const float* x     = (const float*)d_in[0];
    const float* cw    = (const float*)d_in[1];
    const float* gamma = (const float*)d_in[2];
    const float* beta  = (const float*)d_in[3];
    const float* rmean = (const float*)d_in[4];
    const float* rvar  = (const float*)d_in[5];
    float* out = (float*)d_out;
    float* ws  = (float*)d_ws;   // needs 144*4 = 576 B

    hipLaunchKernelGGL(aaf_prep, dim3(1), dim3(128), 0, stream,
                       gamma, beta, rmean, rvar, ws);

    int blocks = NN * HH / 2;           // 1024 blocks: one row-pair x 8 groups
    hipLaunchKernelGGL(aaf_main, dim3(blocks), dim3(512), 0, stream,
                       x, cw, ws, ws + NCH, out);
}